// Round 2
// baseline (2796.504 us; speedup 1.0000x reference)
//
#include <hip/hip_runtime.h>

#define D_IN 2312
#define HID  800
#define NCLS 10
#define BATCH 128
#define TSTEPS 300
#define WIN  50

// ---------------------------------------------------------------------------
// Kernel 1: output X = zeros with input pasted at [idx, idx+50)
// ---------------------------------------------------------------------------
__global__ __launch_bounds__(256) void paste_kernel(
    const float* __restrict__ inp,   // [B][D_IN][WIN]
    const int*   __restrict__ idx,   // [B]
    float*       __restrict__ outX)  // [B][D_IN][T]
{
  int gid  = blockIdx.x * 256 + threadIdx.x;
  int q    = gid % (TSTEPS / 4);
  int rest = gid / (TSTEPS / 4);
  int d    = rest % D_IN;
  int b    = rest / D_IN;
  int ib   = idx[b];
  const float* ip = inp + (size_t)b * (D_IN * WIN) + (size_t)d * WIN;
  int t0 = q * 4;
  float v[4];
#pragma unroll
  for (int e = 0; e < 4; ++e) {
    unsigned w = (unsigned)(t0 + e - ib);
    v[e] = (w < (unsigned)WIN) ? ip[w] : 0.f;
  }
  float4* dst = (float4*)(outX + (size_t)b * (D_IN * TSTEPS) + (size_t)d * TSTEPS + t0);
  *dst = make_float4(v[0], v[1], v[2], v[3]);
}

// ---------------------------------------------------------------------------
// Kernel 2: P[(b*50+s)][j] = sum_d inp[b][d][s] * W1[j][d]
// M=6400 rows (b,s), N=800 cols (j), K=2312. 128x128 tile, BK=16, 256 thr,
// 8x8 microtile split 4+64 in both dims (all LDS b128 reads <=2-way = free).
// ---------------------------------------------------------------------------
#define BM 128
#define BN 128
#define BK 16

__global__ __launch_bounds__(256) void gemm_kernel(
    const float* __restrict__ inp,
    const float* __restrict__ W1,
    float*       __restrict__ P)
{
  __shared__ float As[BK][BM];       // 8 KB
  __shared__ float Bs[BK][BN + 4];   // pad 4 -> write/read 2-way max

  int t  = threadIdx.x;
  int m0 = blockIdx.x * BM;   // 50 tiles, exact
  int n0 = blockIdx.y * BN;   // 7 tiles, last partial (800)

  // A staging: am = t&127 (m), ak = t>>7 selects k half; coalesced along m
  int am = t & 127;
  int ak = t >> 7;
  int r  = m0 + am;
  int bb = r / 50, ss = r - bb * 50;
  const float* aptr = inp + (size_t)bb * (D_IN * WIN) + ss;   // + k*50

  // B staging: 4 rows x 16 k per wave, coalesced along k; transpose into Bs
  int bj = t >> 4;    // 0..15
  int bk = t & 15;    // 0..15

  int tm = (t >> 4) << 2;   // 0..60
  int tn = (t & 15) << 2;   // 0..60

  float acc[8][8] = {};

  for (int k0 = 0; k0 < D_IN; k0 += BK) {
#pragma unroll
    for (int rr = 0; rr < 8; ++rr) {
      int kk = ak * 8 + rr;
      int k  = k0 + kk;
      As[kk][am] = (k < D_IN) ? aptr[k * WIN] : 0.f;
    }
#pragma unroll
    for (int rr = 0; rr < 8; ++rr) {
      int j = bj + 16 * rr;
      int n = n0 + j;
      int k = k0 + bk;
      Bs[bk][j] = (n < HID && k < D_IN) ? W1[(size_t)n * D_IN + k] : 0.f;
    }
    __syncthreads();
#pragma unroll
    for (int kk = 0; kk < BK; ++kk) {
      float4 A0 = *(const float4*)&As[kk][tm];
      float4 A1 = *(const float4*)&As[kk][tm + 64];
      float4 B0 = *(const float4*)&Bs[kk][tn];
      float4 B1 = *(const float4*)&Bs[kk][tn + 64];
      float av[8] = {A0.x, A0.y, A0.z, A0.w, A1.x, A1.y, A1.z, A1.w};
      float bv[8] = {B0.x, B0.y, B0.z, B0.w, B1.x, B1.y, B1.z, B1.w};
#pragma unroll
      for (int i = 0; i < 8; ++i)
#pragma unroll
        for (int j = 0; j < 8; ++j)
          acc[i][j] += av[i] * bv[j];
    }
    __syncthreads();
  }

#pragma unroll
  for (int ih = 0; ih < 2; ++ih) {
#pragma unroll
    for (int i = 0; i < 4; ++i) {
      int row = m0 + tm + ih * 64 + i;
#pragma unroll
      for (int jh = 0; jh < 2; ++jh) {
        int col = n0 + tn + jh * 64;
        if (col < HID) {
          *(float4*)&P[(size_t)row * HID + col] = make_float4(
              acc[ih * 4 + i][jh * 4 + 0], acc[ih * 4 + i][jh * 4 + 1],
              acc[ih * 4 + i][jh * 4 + 2], acc[ih * 4 + i][jh * 4 + 3]);
        }
      }
    }
  }
}

// ---------------------------------------------------------------------------
// Kernel 3: recurrence — ONE WAVE per batch. No barriers in the step loop.
// Lane L owns h1 units j = L + 64r, r=0..12 (padded to 832 with zeros).
// h2/ctrl state replicated on all 64 lanes (butterfly gives all lanes all
// 11 dots), so cs needs no broadcast. Sparse fast path via __ballot.
// ---------------------------------------------------------------------------
__global__ __launch_bounds__(64) void recur_kernel(
    const float* __restrict__ P,    // [6400][HID]
    const float* __restrict__ W2,   // [NCLS][HID]
    const float* __restrict__ b2,   // [NCLS]
    const float* __restrict__ Wc,   // [HID+4]
    const float* __restrict__ bc,   // [1]
    const float* __restrict__ b1,   // [HID]
    const int*   __restrict__ idx,  // [B]
    float*       __restrict__ out)  // [B][NCLS]
{
  __shared__ float sWT[832][12];   // [j][k]: k<10 = W2[k][j], k==10 = Wc[j], k==11 pad

  int L = threadIdx.x;
  int b = blockIdx.x;

  for (int i = L; i < 832 * 12; i += 64) {
    int j = i / 12, k = i - j * 12;
    float v = 0.f;
    if (j < HID) {
      if (k < 10) v = W2[k * HID + j];
      else if (k == 10) v = Wc[j];
    }
    (&sWT[0][0])[i] = v;
  }

  int myidx = idx[b];
  const float* Pb = P + (size_t)b * WIN * HID;

  float m[13], s[13], b1r[13], pn[13];
#pragma unroll
  for (int r = 0; r < 13; ++r) {
    int j = L + 64 * r;
    m[r] = 0.f; s[r] = 0.f;
    b1r[r] = (j < HID) ? b1[j] : 0.f;
  }

  float h2m[10], h2s[10], sum2[10], b2r[10];
#pragma unroll
  for (int c = 0; c < 10; ++c) { h2m[c] = 0.f; h2s[c] = 0.f; sum2[c] = 0.f; b2r[c] = b2[c]; }
  float cm = 0.f, cs = 0.f, bgt = 1.f;
  float bc0 = bc[0];
  float wf0 = Wc[HID], wf1 = Wc[HID + 1], wf2 = Wc[HID + 2], wf3 = Wc[HID + 3];

  __syncthreads();

  // prefetch step 0's P row
  {
    unsigned w = (unsigned)(0 - myidx);
    if (w < (unsigned)WIN) {
      const float* Pr = Pb + (size_t)w * HID;
#pragma unroll
      for (int rr = 0; rr < 13; ++rr) { int j = L + 64 * rr; pn[rr] = (j < HID) ? Pr[j] : 0.f; }
    } else {
#pragma unroll
      for (int rr = 0; rr < 13; ++rr) pn[rr] = 0.f;
    }
  }

  for (int step = 0; step < TSTEPS; ++step) {
    float cur[13];
#pragma unroll
    for (int rr = 0; rr < 13; ++rr) cur[rr] = pn[rr];

    // prefetch next step's P row (address independent of the gate)
    {
      unsigned w = (unsigned)(step + 1 - myidx);
      if (w < (unsigned)WIN) {
        const float* Pr = Pb + (size_t)w * HID;
#pragma unroll
        for (int rr = 0; rr < 13; ++rr) { int j = L + 64 * rr; pn[rr] = (j < HID) ? Pr[j] : 0.f; }
      } else {
#pragma unroll
        for (int rr = 0; rr < 13; ++rr) pn[rr] = 0.f;
      }
    }

    float gateF = (step == 0) ? 1.f : cs;

    // h1 membrane + spike update (always)
    float sany = 0.f;
#pragma unroll
    for (int rr = 0; rr < 13; ++rr) {
      float mv = (s[rr] != 0.f ? 0.f : m[rr] * 0.1f) + cur[rr] * gateF + b1r[rr];
      m[rr] = mv;
      s[rr] = (mv > 0.5f) ? 1.f : 0.f;
      sany += s[rr];
    }
    unsigned long long ball = __ballot(sany != 0.f);

    float d[12];
#pragma unroll
    for (int k = 0; k < 12; ++k) d[k] = 0.f;

    if (ball) {   // wave-uniform branch: any h1 spike this step?
#pragma unroll
      for (int rr = 0; rr < 13; ++rr) {
        if (s[rr] != 0.f) {
          int j = L + 64 * rr;
          const float4* wp = (const float4*)&sWT[j][0];
          float4 w0 = wp[0], w1 = wp[1], w2v = wp[2];
          d[0] += w0.x;  d[1] += w0.y;  d[2]  += w0.z;  d[3]  += w0.w;
          d[4] += w1.x;  d[5] += w1.y;  d[6]  += w1.z;  d[7]  += w1.w;
          d[8] += w2v.x; d[9] += w2v.y; d[10] += w2v.z; d[11] += w2v.w;
        }
      }
      // butterfly all-reduce: every lane ends with all 11 dots
#pragma unroll
      for (int k = 0; k < 11; ++k) {
        float v = d[k];
        v += __shfl_xor(v, 1);
        v += __shfl_xor(v, 2);
        v += __shfl_xor(v, 4);
        v += __shfl_xor(v, 8);
        v += __shfl_xor(v, 16);
        v += __shfl_xor(v, 32);
        d[k] = v;
      }
    }

    // tail, replicated on all lanes (uses OLD cs for gate/bgt/decay)
    bgt += (cs == 1.f) ? 1.f : 0.f;
#pragma unroll
    for (int c = 0; c < 10; ++c) {
      float v = (h2s[c] != 0.f ? 0.f : h2m[c] * 0.1f) + d[c] + b2r[c];
      h2m[c] = v;
      h2s[c] = (v > 0.5f) ? 1.f : 0.f;
      sum2[c] += h2s[c];
    }
    float fq = wf0;
    if ((step & 1) == 0)   fq += wf1;
    if (step % 10 == 0)    fq += wf2;
    if (step % 100 == 0)   fq += wf3;
    float cv = (cs != 0.f ? 0.f : cm * 0.1f) + d[10] + fq + bc0;
    cm = cv;
    cs = (cv > 0.5f) ? 1.f : 0.f;
  }

  if (L == 0) {
#pragma unroll
    for (int c = 0; c < 10; ++c) out[b * NCLS + c] = sum2[c] / bgt;
  }
}

// ---------------------------------------------------------------------------
extern "C" void kernel_launch(void* const* d_in, const int* in_sizes, int n_in,
                              void* d_out, int out_size, void* d_ws, size_t ws_size,
                              hipStream_t stream) {
  const float* inp = (const float*)d_in[0];
  const int*   idx = (const int*)d_in[2];
  const float* W1  = (const float*)d_in[3];
  const float* b1  = (const float*)d_in[4];
  const float* W2  = (const float*)d_in[5];
  const float* b2  = (const float*)d_in[6];
  const float* Wc  = (const float*)d_in[7];
  const float* bc  = (const float*)d_in[8];

  float* out = (float*)d_out;   // [0,1280): rate ; then X
  float* P   = (float*)d_ws;    // [6400][800] fp32 = 20.48 MB

  gemm_kernel<<<dim3(50, 7), 256, 0, stream>>>(inp, W1, P);

  int paste_blocks = (BATCH * D_IN * (TSTEPS / 4)) / 256;   // 86700
  paste_kernel<<<paste_blocks, 256, 0, stream>>>(inp, idx, out + BATCH * NCLS);

  recur_kernel<<<BATCH, 64, 0, stream>>>(P, W2, b2, Wc, bc, b1, idx, out);
}

// Round 3
// 1443.773 us; speedup vs baseline: 1.9369x; 1.9369x over previous
//
#include <hip/hip_runtime.h>

#define D_IN 2312
#define HID  800
#define NCLS 10
#define BATCH 128
#define TSTEPS 300
#define WIN  50

#define GEMM_BLOCKS 1300   // 100 m-tiles x 13 n-tiles, 64x64 each
#define PASTE_BLOCKS 4096
#define TOTQ (BATCH * D_IN * (TSTEPS / 4))   // 22,195,200 float4s of X

// ---------------------------------------------------------------------------
// Fused kernel: blocks [0,1300) = single-wave 64x64 fp32 GEMM tiles
//               blocks [1300, 1300+4096) = grid-stride paste of output X
// GEMM: P[(b*50+s)][j] = sum_d inp[b][d][s] * W1[j][d]
//   M=6400 (b,s), N=800 (j), K=2312 (d). One wave per block, 8x8 micro/lane,
//   register double-buffered global->LDS staging. Barriers are 1-wave (cheap).
// ---------------------------------------------------------------------------
__global__ __launch_bounds__(64) void fused_kernel(
    const float* __restrict__ inp,   // [B][D_IN][WIN]
    const float* __restrict__ W1,    // [HID][D_IN]
    const int*   __restrict__ idx,   // [B]
    float*       __restrict__ P,     // [6400][HID]
    float*       __restrict__ outX)  // [B][D_IN][T]
{
  __shared__ float As[16][64];   // [k][m]
  __shared__ float Bs[16][68];   // [k][n], pad 4 -> write bank-stride 4 (2-way, free)

  int l  = threadIdx.x;
  int bx = blockIdx.x;

  if (bx < GEMM_BLOCKS) {
    // consecutive blocks share the same n-tile -> B col-tile stays hot in L2
    int nt = bx / 100;
    int mt = bx - nt * 100;
    int m0 = mt * 64, n0 = nt * 64;

    int r  = m0 + l;
    int bb = r / 50, ss = r - bb * 50;
    const float* aptr = inp + (size_t)bb * (D_IN * WIN) + ss;   // + k*50

    int bn = l >> 4;      // 0..3  (n sub-group for B staging)
    int bk = l & 15;      // 0..15 (k for B staging)

    int lm = l & 7, ln = l >> 3;
    int tm = lm * 4, tn = ln * 4;

    float aN[16], bN[16];
    // prologue: k0 = 0 slab
#pragma unroll
    for (int k = 0; k < 16; ++k) aN[k] = aptr[k * WIN];
#pragma unroll
    for (int p = 0; p < 16; ++p) {
      int n = n0 + bn + p * 4;
      bN[p] = (n < HID) ? W1[(size_t)n * D_IN + bk] : 0.f;
    }

    float acc[8][8] = {};

    for (int k0 = 0; k0 < D_IN; k0 += 16) {
#pragma unroll
      for (int k = 0; k < 16; ++k) As[k][l] = aN[k];
#pragma unroll
      for (int p = 0; p < 16; ++p) Bs[bk][bn + p * 4] = bN[p];
      __syncthreads();

      // prefetch next slab into registers (hidden under the FMA block)
      int kn0 = k0 + 16;
      if (kn0 < D_IN) {
#pragma unroll
        for (int k = 0; k < 16; ++k) {
          int kk = kn0 + k;
          aN[k] = (kk < D_IN) ? aptr[kk * WIN] : 0.f;
        }
#pragma unroll
        for (int p = 0; p < 16; ++p) {
          int n  = n0 + bn + p * 4;
          int kk = kn0 + bk;
          bN[p] = (n < HID && kk < D_IN) ? W1[(size_t)n * D_IN + kk] : 0.f;
        }
      }

#pragma unroll
      for (int kk = 0; kk < 16; ++kk) {
        float4 A0 = *(const float4*)&As[kk][tm];
        float4 A1 = *(const float4*)&As[kk][tm + 32];
        float4 B0 = *(const float4*)&Bs[kk][tn];
        float4 B1 = *(const float4*)&Bs[kk][tn + 32];
        float av[8] = {A0.x, A0.y, A0.z, A0.w, A1.x, A1.y, A1.z, A1.w};
        float bv[8] = {B0.x, B0.y, B0.z, B0.w, B1.x, B1.y, B1.z, B1.w};
#pragma unroll
        for (int i = 0; i < 8; ++i)
#pragma unroll
          for (int j = 0; j < 8; ++j)
            acc[i][j] += av[i] * bv[j];
      }
      __syncthreads();
    }

#pragma unroll
    for (int ih = 0; ih < 2; ++ih) {
#pragma unroll
      for (int i = 0; i < 4; ++i) {
        int row = m0 + tm + ih * 32 + i;
#pragma unroll
        for (int jh = 0; jh < 2; ++jh) {
          int col = n0 + tn + jh * 32;
          if (col < HID) {
            *(float4*)&P[(size_t)row * HID + col] = make_float4(
                acc[ih * 4 + i][jh * 4 + 0], acc[ih * 4 + i][jh * 4 + 1],
                acc[ih * 4 + i][jh * 4 + 2], acc[ih * 4 + i][jh * 4 + 3]);
          }
        }
      }
    }
  } else {
    // ---- paste path: X = zeros with input window pasted at idx[b] ----
    int tid = (bx - GEMM_BLOCKS) * 64 + l;
    const int stride = PASTE_BLOCKS * 64;
    for (int i = tid; i < TOTQ; i += stride) {
      int q  = i % 75;            // float4 index within a 300-long t row
      int rd = i / 75;            // b*D_IN + d
      int b  = rd / D_IN;
      int d  = rd - b * D_IN;
      int ib = idx[b];
      const float* ip = inp + (size_t)b * (D_IN * WIN) + (size_t)d * WIN;
      int t0 = q * 4;
      float v[4];
#pragma unroll
      for (int e = 0; e < 4; ++e) {
        unsigned w = (unsigned)(t0 + e - ib);
        v[e] = (w < (unsigned)WIN) ? ip[w] : 0.f;
      }
      *(float4*)&outX[(size_t)rd * TSTEPS + t0] = make_float4(v[0], v[1], v[2], v[3]);
    }
  }
}

// ---------------------------------------------------------------------------
// Recurrence — ONE WAVE per batch, no barriers in the step loop.
// Lane L owns h1 units j = L + 64r, r=0..12. h2/ctrl replicated on all lanes.
// ---------------------------------------------------------------------------
__global__ __launch_bounds__(64) void recur_kernel(
    const float* __restrict__ P,    // [6400][HID]
    const float* __restrict__ W2,   // [NCLS][HID]
    const float* __restrict__ b2,   // [NCLS]
    const float* __restrict__ Wc,   // [HID+4]
    const float* __restrict__ bc,   // [1]
    const float* __restrict__ b1,   // [HID]
    const int*   __restrict__ idx,  // [B]
    float*       __restrict__ out)  // [B][NCLS]
{
  __shared__ float sWT[832][12];   // [j][k]: k<10 = W2[k][j], k==10 = Wc[j]

  int L = threadIdx.x;
  int b = blockIdx.x;

  for (int i = L; i < 832 * 12; i += 64) {
    int j = i / 12, k = i - j * 12;
    float v = 0.f;
    if (j < HID) {
      if (k < 10) v = W2[k * HID + j];
      else if (k == 10) v = Wc[j];
    }
    (&sWT[0][0])[i] = v;
  }

  int myidx = idx[b];
  const float* Pb = P + (size_t)b * WIN * HID;

  float m[13], s[13], b1r[13], pn[13];
#pragma unroll
  for (int r = 0; r < 13; ++r) {
    int j = L + 64 * r;
    m[r] = 0.f; s[r] = 0.f;
    b1r[r] = (j < HID) ? b1[j] : 0.f;
  }

  float h2m[10], h2s[10], sum2[10], b2r[10];
#pragma unroll
  for (int c = 0; c < 10; ++c) { h2m[c] = 0.f; h2s[c] = 0.f; sum2[c] = 0.f; b2r[c] = b2[c]; }
  float cm = 0.f, cs = 0.f, bgt = 1.f;
  float bc0 = bc[0];
  float wf0 = Wc[HID], wf1 = Wc[HID + 1], wf2 = Wc[HID + 2], wf3 = Wc[HID + 3];

  __syncthreads();

  {
    unsigned w = (unsigned)(0 - myidx);
    if (w < (unsigned)WIN) {
      const float* Pr = Pb + (size_t)w * HID;
#pragma unroll
      for (int rr = 0; rr < 13; ++rr) { int j = L + 64 * rr; pn[rr] = (j < HID) ? Pr[j] : 0.f; }
    } else {
#pragma unroll
      for (int rr = 0; rr < 13; ++rr) pn[rr] = 0.f;
    }
  }

  for (int step = 0; step < TSTEPS; ++step) {
    float cur[13];
#pragma unroll
    for (int rr = 0; rr < 13; ++rr) cur[rr] = pn[rr];

    {
      unsigned w = (unsigned)(step + 1 - myidx);
      if (w < (unsigned)WIN) {
        const float* Pr = Pb + (size_t)w * HID;
#pragma unroll
        for (int rr = 0; rr < 13; ++rr) { int j = L + 64 * rr; pn[rr] = (j < HID) ? Pr[j] : 0.f; }
      } else {
#pragma unroll
        for (int rr = 0; rr < 13; ++rr) pn[rr] = 0.f;
      }
    }

    float gateF = (step == 0) ? 1.f : cs;

    float sany = 0.f;
#pragma unroll
    for (int rr = 0; rr < 13; ++rr) {
      float mv = (s[rr] != 0.f ? 0.f : m[rr] * 0.1f) + cur[rr] * gateF + b1r[rr];
      m[rr] = mv;
      s[rr] = (mv > 0.5f) ? 1.f : 0.f;
      sany += s[rr];
    }
    unsigned long long ball = __ballot(sany != 0.f);

    float d[12];
#pragma unroll
    for (int k = 0; k < 12; ++k) d[k] = 0.f;

    if (ball) {
#pragma unroll
      for (int rr = 0; rr < 13; ++rr) {
        if (s[rr] != 0.f) {
          int j = L + 64 * rr;
          const float4* wp = (const float4*)&sWT[j][0];
          float4 w0 = wp[0], w1 = wp[1], w2v = wp[2];
          d[0] += w0.x;  d[1] += w0.y;  d[2]  += w0.z;  d[3]  += w0.w;
          d[4] += w1.x;  d[5] += w1.y;  d[6]  += w1.z;  d[7]  += w1.w;
          d[8] += w2v.x; d[9] += w2v.y; d[10] += w2v.z; d[11] += w2v.w;
        }
      }
#pragma unroll
      for (int k = 0; k < 11; ++k) {
        float v = d[k];
        v += __shfl_xor(v, 1);
        v += __shfl_xor(v, 2);
        v += __shfl_xor(v, 4);
        v += __shfl_xor(v, 8);
        v += __shfl_xor(v, 16);
        v += __shfl_xor(v, 32);
        d[k] = v;
      }
    }

    bgt += (cs == 1.f) ? 1.f : 0.f;
#pragma unroll
    for (int c = 0; c < 10; ++c) {
      float v = (h2s[c] != 0.f ? 0.f : h2m[c] * 0.1f) + d[c] + b2r[c];
      h2m[c] = v;
      h2s[c] = (v > 0.5f) ? 1.f : 0.f;
      sum2[c] += h2s[c];
    }
    float fq = wf0;
    if ((step & 1) == 0)   fq += wf1;
    if (step % 10 == 0)    fq += wf2;
    if (step % 100 == 0)   fq += wf3;
    float cv = (cs != 0.f ? 0.f : cm * 0.1f) + d[10] + fq + bc0;
    cm = cv;
    cs = (cv > 0.5f) ? 1.f : 0.f;
  }

  if (L == 0) {
#pragma unroll
    for (int c = 0; c < 10; ++c) out[b * NCLS + c] = sum2[c] / bgt;
  }
}

// ---------------------------------------------------------------------------
extern "C" void kernel_launch(void* const* d_in, const int* in_sizes, int n_in,
                              void* d_out, int out_size, void* d_ws, size_t ws_size,
                              hipStream_t stream) {
  const float* inp = (const float*)d_in[0];
  const int*   idx = (const int*)d_in[2];
  const float* W1  = (const float*)d_in[3];
  const float* b1  = (const float*)d_in[4];
  const float* W2  = (const float*)d_in[5];
  const float* b2  = (const float*)d_in[6];
  const float* Wc  = (const float*)d_in[7];
  const float* bc  = (const float*)d_in[8];

  float* out = (float*)d_out;   // [0,1280): rate ; then X
  float* P   = (float*)d_ws;    // [6400][800] fp32 = 20.48 MB

  fused_kernel<<<GEMM_BLOCKS + PASTE_BLOCKS, 64, 0, stream>>>(
      inp, W1, idx, P, out + BATCH * NCLS);

  recur_kernel<<<BATCH, 64, 0, stream>>>(P, W2, b2, Wc, bc, b1, idx, out);
}

// Round 4
// 1251.548 us; speedup vs baseline: 2.2344x; 1.1536x over previous
//
#include <hip/hip_runtime.h>

#define D_IN 2312
#define HID  800
#define NCLS 10
#define BATCH 128
#define TSTEPS 300
#define WIN  50

#define MT 32
#define NT 64
#define BKK 16
#define NTILES_M 200                       // 6400/32
#define NTILES_N 13
#define GEMM_BLOCKS (NTILES_M * NTILES_N)  // 2600 single-wave tiles
#define PASTE_BLOCKS 4096
#define TOTQ (BATCH * D_IN * (TSTEPS / 4)) // 22,195,200 float4s of X

// ---------------------------------------------------------------------------
// Fused: blocks [0,2600) = single-wave 32x64 fp32 GEMM tiles (split-M for
// occupancy: 2600 waves = 2.54 waves/SIMD). blocks [2600,+4096) = paste of X.
// GEMM: P[(b*50+s)][j] = sum_d inp[b][d][s] * W1[j][d]; k-order sequential
// (bit-identical P vs previous rounds).
// ---------------------------------------------------------------------------
__global__ __launch_bounds__(64) void fused_kernel(
    const float* __restrict__ inp,   // [B][D_IN][WIN]
    const float* __restrict__ W1,    // [HID][D_IN]
    const int*   __restrict__ idx,   // [B]
    float*       __restrict__ P,     // [6400][HID]
    float*       __restrict__ outX)  // [B][D_IN][T]
{
  __shared__ float As[BKK][MT];       // 2 KB
  __shared__ float Bs[BKK][NT + 4];   // 4.25 KB

  int l  = threadIdx.x;
  int bx = blockIdx.x;

  if (bx < GEMM_BLOCKS) {
    int nt = bx / NTILES_M;            // consecutive blocks share n-tile (L2)
    int mt = bx - nt * NTILES_M;
    int m0 = mt * MT, n0 = nt * NT;

    // A staging: lane covers (am, 8 k's)
    int am = l & 31;
    int ak = l >> 5;                   // 0..1 -> k-half
    int r  = m0 + am;
    int bb = r / 50, ss = r - bb * 50;
    const float* aptr = inp + (size_t)bb * (D_IN * WIN) + ss;   // + k*50

    // B staging: 64 n x 16 k, coalesced along k
    int bn = l >> 4;                   // 0..3
    int bk = l & 15;                   // 0..15

    int lm = l >> 3;                   // 0..7 -> m
    int ln = l & 7;                    // 0..7 -> n
    int tm = lm * 4, tn = ln * 8;

    float aN[8], bN[16];
#pragma unroll
    for (int q = 0; q < 8; ++q) aN[q] = aptr[(ak * 8 + q) * WIN];
#pragma unroll
    for (int p = 0; p < 16; ++p) {
      int n = n0 + bn + 4 * p;
      bN[p] = (n < HID) ? W1[(size_t)n * D_IN + bk] : 0.f;
    }

    float acc[4][8] = {};

    for (int k0 = 0; k0 < D_IN; k0 += BKK) {   // 145 slabs, last partial
#pragma unroll
      for (int q = 0; q < 8; ++q) As[ak * 8 + q][am] = aN[q];
#pragma unroll
      for (int p = 0; p < 16; ++p) Bs[bk][bn + 4 * p] = bN[p];
      __syncthreads();

      int kn0 = k0 + BKK;
      if (kn0 < D_IN) {
#pragma unroll
        for (int q = 0; q < 8; ++q) {
          int kk = kn0 + ak * 8 + q;
          aN[q] = (kk < D_IN) ? aptr[kk * WIN] : 0.f;
        }
#pragma unroll
        for (int p = 0; p < 16; ++p) {
          int n  = n0 + bn + 4 * p;
          int kk = kn0 + bk;
          bN[p] = (n < HID && kk < D_IN) ? W1[(size_t)n * D_IN + kk] : 0.f;
        }
      }

#pragma unroll
      for (int kk = 0; kk < BKK; ++kk) {
        float4 A0 = *(const float4*)&As[kk][tm];
        float4 B0 = *(const float4*)&Bs[kk][tn];
        float4 B1 = *(const float4*)&Bs[kk][tn + 4];
        float av[4] = {A0.x, A0.y, A0.z, A0.w};
        float bv[8] = {B0.x, B0.y, B0.z, B0.w, B1.x, B1.y, B1.z, B1.w};
#pragma unroll
        for (int i = 0; i < 4; ++i)
#pragma unroll
          for (int j = 0; j < 8; ++j)
            acc[i][j] += av[i] * bv[j];
      }
      __syncthreads();
    }

    if (n0 + tn < HID) {   // HID multiple of 8 -> whole 8-col group valid
#pragma unroll
      for (int i = 0; i < 4; ++i) {
        int row = m0 + tm + i;
        *(float4*)&P[(size_t)row * HID + n0 + tn] =
            make_float4(acc[i][0], acc[i][1], acc[i][2], acc[i][3]);
        *(float4*)&P[(size_t)row * HID + n0 + tn + 4] =
            make_float4(acc[i][4], acc[i][5], acc[i][6], acc[i][7]);
      }
    }
  } else {
    // ---- paste path ----
    int tid = (bx - GEMM_BLOCKS) * 64 + l;
    const int stride = PASTE_BLOCKS * 64;
    for (int i = tid; i < TOTQ; i += stride) {
      int q  = i % 75;
      int rd = i / 75;
      int b  = rd / D_IN;
      int d  = rd - b * D_IN;
      int ib = idx[b];
      const float* ip = inp + (size_t)b * (D_IN * WIN) + (size_t)d * WIN;
      int t0 = q * 4;
      float v[4];
#pragma unroll
      for (int e = 0; e < 4; ++e) {
        unsigned w = (unsigned)(t0 + e - ib);
        v[e] = (w < (unsigned)WIN) ? ip[w] : 0.f;
      }
      *(float4*)&outX[(size_t)rd * TSTEPS + t0] = make_float4(v[0], v[1], v[2], v[3]);
    }
  }
}

// ---------------------------------------------------------------------------
// Recurrence v2 — one wave per batch. Critical path per step: h1 update +
// Wc gather (13 conflict-free ds_read_b32) + ONE 6-deep butterfly + cm/cs.
// h2 class dots DEFERRED: per-step spike ballots buffered in LDS, flushed
// with full ILP (branchless FMA accumulation + batched butterflies) plus the
// trivial 10-class serial chain over gap steps (dot=0). Spike decisions are
// exact; internal membrane values never surface in the output.
// ---------------------------------------------------------------------------
__global__ __launch_bounds__(64) void recur_kernel(
    const float* __restrict__ P,    // [6400][HID]
    const float* __restrict__ W2,   // [NCLS][HID]
    const float* __restrict__ b2,   // [NCLS]
    const float* __restrict__ Wc,   // [HID+4]
    const float* __restrict__ bc,   // [1]
    const float* __restrict__ b1,   // [HID]
    const int*   __restrict__ idx,  // [B]
    float*       __restrict__ out)  // [B][NCLS]
{
  __shared__ float sW2t[832][12];               // [j][c], c<10 valid; 39.9 KB
  __shared__ float sWc[832];                    // 3.3 KB
  __shared__ unsigned long long sMask[64][13];  // 6.7 KB
  __shared__ int sSteps[64];

  int L = threadIdx.x;
  int b = blockIdx.x;

#pragma unroll
  for (int c = 0; c < 10; ++c)
    for (int base = 0; base < 832; base += 64) {
      int j = base + L;
      sW2t[j][c] = (j < HID) ? W2[c * HID + j] : 0.f;
    }
  for (int base = 0; base < 832; base += 64) {
    int j = base + L;
    sWc[j] = (j < HID) ? Wc[j] : 0.f;
  }

  int myidx = idx[b];
  const float* Pb = P + (size_t)b * WIN * HID;

  float m[13], s[13], b1r[13], pn[13];
#pragma unroll
  for (int rr = 0; rr < 13; ++rr) {
    int j = L + 64 * rr;
    m[rr] = 0.f; s[rr] = 0.f;
    b1r[rr] = (j < HID) ? b1[j] : 0.f;
  }

  float h2m[10], h2s[10], sum2[10], b2r[10];
#pragma unroll
  for (int c = 0; c < 10; ++c) { h2m[c] = 0.f; h2s[c] = 0.f; sum2[c] = 0.f; b2r[c] = b2[c]; }
  float cm = 0.f, cs = 0.f, bgt = 1.f;
  float bc0 = bc[0];
  float wf0 = Wc[HID], wf1 = Wc[HID + 1], wf2 = Wc[HID + 2], wf3 = Wc[HID + 3];

  int cnt = 0;      // buffered spike-steps (wave-uniform)
  int tproc = 0;    // h2 chain processed through t < tproc

  auto h2gap = [&]() {   // one h2 step with dot = 0
#pragma unroll
    for (int c = 0; c < 10; ++c) {
      float v = (h2s[c] != 0.f ? 0.f : h2m[c] * 0.1f) + b2r[c];
      h2m[c] = v;
      h2s[c] = (v > 0.5f) ? 1.f : 0.f;
      sum2[c] += h2s[c];
    }
  };

  auto flush = [&]() {
    for (int u = 0; u < cnt; ++u) {
      int ts = sSteps[u];
      for (; tproc < ts; ++tproc) h2gap();
      float acc[10];
#pragma unroll
      for (int c = 0; c < 10; ++c) acc[c] = 0.f;
#pragma unroll
      for (int rr = 0; rr < 13; ++rr) {
        unsigned long long msk = sMask[u][rr];               // broadcast read
        float f = (float)((unsigned)((msk >> L) & 1ull));
        const float4* row = (const float4*)&sW2t[L + 64 * rr][0];
        float4 r0 = row[0], r1 = row[1], r2 = row[2];
        acc[0] += f * r0.x; acc[1] += f * r0.y; acc[2] += f * r0.z; acc[3] += f * r0.w;
        acc[4] += f * r1.x; acc[5] += f * r1.y; acc[6] += f * r1.z; acc[7] += f * r1.w;
        acc[8] += f * r2.x; acc[9] += f * r2.y;
      }
#pragma unroll
      for (int c = 0; c < 10; ++c) {
        float v = acc[c];
        v += __shfl_xor(v, 1);
        v += __shfl_xor(v, 2);
        v += __shfl_xor(v, 4);
        v += __shfl_xor(v, 8);
        v += __shfl_xor(v, 16);
        v += __shfl_xor(v, 32);
        acc[c] = v;
      }
#pragma unroll
      for (int c = 0; c < 10; ++c) {
        float v = (h2s[c] != 0.f ? 0.f : h2m[c] * 0.1f) + acc[c] + b2r[c];
        h2m[c] = v;
        h2s[c] = (v > 0.5f) ? 1.f : 0.f;
        sum2[c] += h2s[c];
      }
      ++tproc;
    }
    cnt = 0;
  };

  __syncthreads();

  // prefetch step 0's P row
  {
    unsigned w = (unsigned)(0 - myidx);
    if (w < (unsigned)WIN) {
      const float* Pr = Pb + (size_t)w * HID;
#pragma unroll
      for (int rr = 0; rr < 13; ++rr) { int j = L + 64 * rr; pn[rr] = (j < HID) ? Pr[j] : 0.f; }
    } else {
#pragma unroll
      for (int rr = 0; rr < 13; ++rr) pn[rr] = 0.f;
    }
  }

  for (int step = 0; step < TSTEPS; ++step) {
    float cur[13];
#pragma unroll
    for (int rr = 0; rr < 13; ++rr) cur[rr] = pn[rr];

    {   // prefetch next step's row (address independent of gate)
      unsigned w = (unsigned)(step + 1 - myidx);
      if (w < (unsigned)WIN) {
        const float* Pr = Pb + (size_t)w * HID;
#pragma unroll
        for (int rr = 0; rr < 13; ++rr) { int j = L + 64 * rr; pn[rr] = (j < HID) ? Pr[j] : 0.f; }
      } else {
#pragma unroll
        for (int rr = 0; rr < 13; ++rr) pn[rr] = 0.f;
      }
    }

    float gate = (step == 0) ? 1.f : cs;

    float sany = 0.f;
#pragma unroll
    for (int rr = 0; rr < 13; ++rr) {
      float mv = (s[rr] != 0.f ? 0.f : m[rr] * 0.1f) + cur[rr] * gate + b1r[rr];
      m[rr] = mv;
      s[rr] = (mv > 0.5f) ? 1.f : 0.f;
      sany += s[rr];
    }
    unsigned long long ball = __ballot(sany != 0.f);

    float ctrl = 0.f;
    if (ball) {
      // inline ctrl dot (latency-critical): branchless gather of Wc
      float cacc = 0.f;
#pragma unroll
      for (int rr = 0; rr < 13; ++rr) cacc += s[rr] * sWc[L + 64 * rr];
      cacc += __shfl_xor(cacc, 1);
      cacc += __shfl_xor(cacc, 2);
      cacc += __shfl_xor(cacc, 4);
      cacc += __shfl_xor(cacc, 8);
      cacc += __shfl_xor(cacc, 16);
      cacc += __shfl_xor(cacc, 32);
      ctrl = cacc;

      // record spike ballots for deferred h2
      unsigned long long mym = 0ull;
#pragma unroll
      for (int rr = 0; rr < 13; ++rr) {
        unsigned long long bl = __ballot(s[rr] != 0.f);
        if (L == rr) mym = bl;
      }
      if (L < 13) sMask[cnt][L] = mym;
      if (L == 0) sSteps[cnt] = step;
      ++cnt;
      if (cnt == 64) flush();
    }

    // ctrl neuron + budget (old cs semantics)
    bgt += (cs == 1.f) ? 1.f : 0.f;
    float fq = wf0;
    if ((step & 1) == 0)   fq += wf1;
    if (step % 10 == 0)    fq += wf2;
    if (step % 100 == 0)   fq += wf3;
    float cv = (cs != 0.f ? 0.f : cm * 0.1f) + ctrl + fq + bc0;
    cm = cv;
    cs = (cv > 0.5f) ? 1.f : 0.f;
  }

  flush();
  for (; tproc < TSTEPS; ++tproc) h2gap();

  if (L == 0) {
#pragma unroll
    for (int c = 0; c < 10; ++c) out[b * NCLS + c] = sum2[c] / bgt;
  }
}

// ---------------------------------------------------------------------------
extern "C" void kernel_launch(void* const* d_in, const int* in_sizes, int n_in,
                              void* d_out, int out_size, void* d_ws, size_t ws_size,
                              hipStream_t stream) {
  const float* inp = (const float*)d_in[0];
  const int*   idx = (const int*)d_in[2];
  const float* W1  = (const float*)d_in[3];
  const float* b1  = (const float*)d_in[4];
  const float* W2  = (const float*)d_in[5];
  const float* b2  = (const float*)d_in[6];
  const float* Wc  = (const float*)d_in[7];
  const float* bc  = (const float*)d_in[8];

  float* out = (float*)d_out;   // [0,1280): rate ; then X
  float* P   = (float*)d_ws;    // [6400][800] fp32 = 20.48 MB

  fused_kernel<<<GEMM_BLOCKS + PASTE_BLOCKS, 64, 0, stream>>>(
      inp, W1, idx, P, out + BATCH * NCLS);

  recur_kernel<<<BATCH, 64, 0, stream>>>(P, W2, b2, Wc, bc, b1, idx, out);
}

// Round 5
// 1228.280 us; speedup vs baseline: 2.2768x; 1.0189x over previous
//
#include <hip/hip_runtime.h>

#define D_IN 2312
#define HID  800
#define NCLS 10
#define BATCH 128
#define TSTEPS 300
#define WIN  50

#define MT 32
#define NT 32
#define BKK 16
#define NTILES_M 200                       // 6400/32
#define NTILES_N 25                        // 800/32, exact
#define GEMM_BLOCKS (NTILES_M * NTILES_N)  // 5000 single-wave tiles
#define PASTE_BLOCKS 4096
#define TOTQ (BATCH * D_IN * (TSTEPS / 4)) // 22,195,200 float4s of X

// ---------------------------------------------------------------------------
// Fused: blocks [0,5000) = single-wave 32x32 fp32 GEMM tiles (4.9 waves/SIMD
// for latency hiding). blocks [5000,+4096) = grid-stride paste of X.
// GEMM: P[(b*50+s)][j] = sum_d inp[b][d][s] * W1[j][d]; k-order sequential
// (bit-identical P vs rounds 3/4).
// ---------------------------------------------------------------------------
__global__ __launch_bounds__(64) void fused_kernel(
    const float* __restrict__ inp,   // [B][D_IN][WIN]
    const float* __restrict__ W1,    // [HID][D_IN]
    const int*   __restrict__ idx,   // [B]
    float*       __restrict__ P,     // [6400][HID]
    float*       __restrict__ outX)  // [B][D_IN][T]
{
  __shared__ float As[BKK][MT];       // 2 KB
  __shared__ float Bs[BKK][NT + 4];   // 2.25 KB

  int l  = threadIdx.x;
  int bx = blockIdx.x;

  if (bx < GEMM_BLOCKS) {
    int nt = bx / NTILES_M;            // consecutive blocks share n-tile (L2)
    int mt = bx - nt * NTILES_M;
    int m0 = mt * MT, n0 = nt * NT;

    // A staging: lane covers (am, 8 k's); coalesced along m (s-contiguous)
    int am = l & 31;
    int ak = l >> 5;                   // 0..1 -> k-half
    int r  = m0 + am;
    int bb = r / 50, ss = r - bb * 50;
    const float* aptr = inp + (size_t)bb * (D_IN * WIN) + ss;   // + k*50

    // B staging: 32 n x 16 k, coalesced along k
    int bn = l >> 4;                   // 0..3
    int bk = l & 15;                   // 0..15

    int lm = l & 7;                    // m micro-group
    int ln = l >> 3;                   // n micro-group
    int tm = lm * 4, tn = ln * 4;

    float aN[8], bN[8];
#pragma unroll
    for (int q = 0; q < 8; ++q) aN[q] = aptr[(ak * 8 + q) * WIN];
#pragma unroll
    for (int p = 0; p < 8; ++p)
      bN[p] = W1[(size_t)(n0 + bn + 4 * p) * D_IN + bk];

    float acc[4][4] = {};

    for (int k0 = 0; k0 < D_IN; k0 += BKK) {   // 145 slabs, last partial
#pragma unroll
      for (int q = 0; q < 8; ++q) As[ak * 8 + q][am] = aN[q];
#pragma unroll
      for (int p = 0; p < 8; ++p) Bs[bk][bn + 4 * p] = bN[p];
      __syncthreads();

      int kn0 = k0 + BKK;
      if (kn0 < D_IN) {
#pragma unroll
        for (int q = 0; q < 8; ++q) {
          int kk = kn0 + ak * 8 + q;
          aN[q] = (kk < D_IN) ? aptr[kk * WIN] : 0.f;
        }
#pragma unroll
        for (int p = 0; p < 8; ++p) {
          int kk = kn0 + bk;
          bN[p] = (kk < D_IN) ? W1[(size_t)(n0 + bn + 4 * p) * D_IN + kk] : 0.f;
        }
      }

#pragma unroll
      for (int kk = 0; kk < BKK; ++kk) {
        float4 A0 = *(const float4*)&As[kk][tm];
        float4 B0 = *(const float4*)&Bs[kk][tn];
        float av[4] = {A0.x, A0.y, A0.z, A0.w};
        float bv[4] = {B0.x, B0.y, B0.z, B0.w};
#pragma unroll
        for (int i = 0; i < 4; ++i)
#pragma unroll
          for (int j = 0; j < 4; ++j)
            acc[i][j] += av[i] * bv[j];
      }
      __syncthreads();
    }

#pragma unroll
    for (int i = 0; i < 4; ++i) {
      int row = m0 + tm + i;
      *(float4*)&P[(size_t)row * HID + n0 + tn] =
          make_float4(acc[i][0], acc[i][1], acc[i][2], acc[i][3]);
    }
  } else {
    // ---- paste path: X = zeros with input window pasted at idx[b] ----
    int tid = (bx - GEMM_BLOCKS) * 64 + l;
    const int stride = PASTE_BLOCKS * 64;
    for (int i = tid; i < TOTQ; i += stride) {
      int q  = i % 75;
      int rd = i / 75;
      int b  = rd / D_IN;
      int d  = rd - b * D_IN;
      int ib = idx[b];
      const float* ip = inp + (size_t)b * (D_IN * WIN) + (size_t)d * WIN;
      int t0 = q * 4;
      float v[4];
#pragma unroll
      for (int e = 0; e < 4; ++e) {
        unsigned w = (unsigned)(t0 + e - ib);
        v[e] = (w < (unsigned)WIN) ? ip[w] : 0.f;
      }
      *(float4*)&outX[(size_t)rd * TSTEPS + t0] = make_float4(v[0], v[1], v[2], v[3]);
    }
  }
}

// ---------------------------------------------------------------------------
// Recurrence v3 — one wave per batch, minimal live registers (no spill).
// Main loop live set: m[13] + 13-bit spike mask + b1r[13] + ctrl state ~ 50
// VGPRs. h2 is fully deferred: spike masks stored per-lane as u16 in LDS
// (capacity 300, no mid-loop flush), h2 chain replayed once after the loop
// from W2 held row-major in LDS (stride-1, conflict-free).
// ---------------------------------------------------------------------------
__global__ __launch_bounds__(64) void recur_kernel(
    const float* __restrict__ P,    // [6400][HID]
    const float* __restrict__ W2,   // [NCLS][HID]
    const float* __restrict__ b2,   // [NCLS]
    const float* __restrict__ Wc,   // [HID+4]
    const float* __restrict__ bc,   // [1]
    const float* __restrict__ b1,   // [HID]
    const int*   __restrict__ idx,  // [B]
    float*       __restrict__ out)  // [B][NCLS]
{
  __shared__ float sW2row[NCLS][832];           // 33.3 KB, row-major
  __shared__ float sWc[832];                    // 3.3 KB
  __shared__ unsigned short sM[TSTEPS][64];     // 38.4 KB spike masks
  __shared__ int sSteps[TSTEPS];                // 1.2 KB

  int L = threadIdx.x;
  int b = blockIdx.x;

#pragma unroll
  for (int c = 0; c < NCLS; ++c)
    for (int base = 0; base < 832; base += 64) {
      int j = base + L;
      sW2row[c][j] = (j < HID) ? W2[c * HID + j] : 0.f;
    }
  for (int base = 0; base < 832; base += 64) {
    int j = base + L;
    sWc[j] = (j < HID) ? Wc[j] : 0.f;
  }

  int myidx = idx[b];
  const float* Pb = P + (size_t)b * WIN * HID;

  float m[13], b1r[13];
  unsigned smask = 0;
#pragma unroll
  for (int rr = 0; rr < 13; ++rr) {
    int j = L + 64 * rr;
    m[rr] = 0.f;
    b1r[rr] = (j < HID) ? b1[j] : 0.f;
  }

  float cm = 0.f, cs = 0.f, bgt = 1.f;
  float bc0 = bc[0];
  float wf0 = Wc[HID], wf1 = Wc[HID + 1], wf2 = Wc[HID + 2], wf3 = Wc[HID + 3];
  int cnt = 0;

  __syncthreads();

  for (int step = 0; step < TSTEPS; ++step) {
    float gate = (step == 0) ? 1.f : cs;
    unsigned w = (unsigned)(step - myidx);
    float cur[13];
    if (w < (unsigned)WIN && gate != 0.f) {
      const float* Pr = Pb + (size_t)w * HID;
#pragma unroll
      for (int rr = 0; rr < 13; ++rr) {
        int j = L + 64 * rr;
        cur[rr] = (j < HID) ? Pr[j] : 0.f;
      }
    } else {
#pragma unroll
      for (int rr = 0; rr < 13; ++rr) cur[rr] = 0.f;
    }

    unsigned nmask = 0;
#pragma unroll
    for (int rr = 0; rr < 13; ++rr) {
      float mprev = ((smask >> rr) & 1u) ? 0.f : m[rr] * 0.1f;
      float mv = mprev + cur[rr] * gate + b1r[rr];
      m[rr] = mv;
      nmask |= (mv > 0.5f) ? (1u << rr) : 0u;
    }
    smask = nmask;

    unsigned long long ball = __ballot(smask != 0u);

    float ctrl = 0.f;
    if (ball) {
      // inline ctrl dot: branchless FMA over own units (LDS stride-64, free)
      float cacc = 0.f;
#pragma unroll
      for (int rr = 0; rr < 13; ++rr) {
        float f = (float)((smask >> rr) & 1u);
        cacc = fmaf(f, sWc[L + 64 * rr], cacc);
      }
      cacc += __shfl_xor(cacc, 1);
      cacc += __shfl_xor(cacc, 2);
      cacc += __shfl_xor(cacc, 4);
      cacc += __shfl_xor(cacc, 8);
      cacc += __shfl_xor(cacc, 16);
      cacc += __shfl_xor(cacc, 32);
      ctrl = cacc;

      sM[cnt][L] = (unsigned short)smask;
      if (L == 0) sSteps[cnt] = step;
      ++cnt;
    }

    // ctrl neuron + budget (old cs semantics)
    bgt += (cs == 1.f) ? 1.f : 0.f;
    float fq = wf0;
    if ((step & 1) == 0)   fq += wf1;
    if (step % 10 == 0)    fq += wf2;
    if (step % 100 == 0)   fq += wf3;
    float cv = (cs != 0.f ? 0.f : cm * 0.1f) + ctrl + fq + bc0;
    cm = cv;
    cs = (cv > 0.5f) ? 1.f : 0.f;
  }

  // ---- deferred h2 chain: replay 300 steps, dots only at recorded steps ----
  float h2m[10], h2s[10], sum2[10], b2r[10];
#pragma unroll
  for (int c = 0; c < NCLS; ++c) { h2m[c] = 0.f; h2s[c] = 0.f; sum2[c] = 0.f; b2r[c] = b2[c]; }

  int ptr = 0;
  for (int t = 0; t < TSTEPS; ++t) {
    float dot[10];
#pragma unroll
    for (int c = 0; c < NCLS; ++c) dot[c] = 0.f;

    if (ptr < cnt && sSteps[ptr] == t) {
      unsigned msk = (unsigned)sM[ptr][L];
#pragma unroll
      for (int rr = 0; rr < 13; ++rr) {
        float f = (float)((msk >> rr) & 1u);
        int j = L + 64 * rr;
#pragma unroll
        for (int c = 0; c < NCLS; ++c)
          dot[c] = fmaf(f, sW2row[c][j], dot[c]);
      }
#pragma unroll
      for (int c = 0; c < NCLS; ++c) {
        float v = dot[c];
        v += __shfl_xor(v, 1);
        v += __shfl_xor(v, 2);
        v += __shfl_xor(v, 4);
        v += __shfl_xor(v, 8);
        v += __shfl_xor(v, 16);
        v += __shfl_xor(v, 32);
        dot[c] = v;
      }
      ++ptr;
    }

#pragma unroll
    for (int c = 0; c < NCLS; ++c) {
      float v = (h2s[c] != 0.f ? 0.f : h2m[c] * 0.1f) + dot[c] + b2r[c];
      h2m[c] = v;
      h2s[c] = (v > 0.5f) ? 1.f : 0.f;
      sum2[c] += h2s[c];
    }
  }

  if (L == 0) {
#pragma unroll
    for (int c = 0; c < NCLS; ++c) out[b * NCLS + c] = sum2[c] / bgt;
  }
}

// ---------------------------------------------------------------------------
extern "C" void kernel_launch(void* const* d_in, const int* in_sizes, int n_in,
                              void* d_out, int out_size, void* d_ws, size_t ws_size,
                              hipStream_t stream) {
  const float* inp = (const float*)d_in[0];
  const int*   idx = (const int*)d_in[2];
  const float* W1  = (const float*)d_in[3];
  const float* b1  = (const float*)d_in[4];
  const float* W2  = (const float*)d_in[5];
  const float* b2  = (const float*)d_in[6];
  const float* Wc  = (const float*)d_in[7];
  const float* bc  = (const float*)d_in[8];

  float* out = (float*)d_out;   // [0,1280): rate ; then X
  float* P   = (float*)d_ws;    // [6400][800] fp32 = 20.48 MB

  fused_kernel<<<GEMM_BLOCKS + PASTE_BLOCKS, 64, 0, stream>>>(
      inp, W1, idx, P, out + BATCH * NCLS);

  recur_kernel<<<BATCH, 64, 0, stream>>>(P, W2, b2, Wc, bc, b1, idx, out);
}